// Round 15
// baseline (257.490 us; speedup 1.0000x reference)
//
#include <hip/hip_runtime.h>
#include <math.h>

#define B_ 2
#define N_ 25000
#define E_ 400000
#define D_ 128
#define NRBF 64

#define TPB 256               // 4 waves
#define TILE 64               // edges per tile-step (16/wave)
#define NTILES 25
#define EPB (TILE * NTILES)   // 1600 edges per block
#define WCH (EPB / 4)         // 400 edges per wave
#define GCH (EPB / 16)        // 100 edges per (wave, lane-quad) chunk
#define NBLK (E_ / EPB)       // 250 blocks per batch

typedef short bf8   __attribute__((ext_vector_type(8)));   // MFMA A/B frag (8 bf16)
typedef float f32x4 __attribute__((ext_vector_type(4)));   // MFMA C/D frag
typedef float vf8   __attribute__((ext_vector_type(8)));
typedef float vf16  __attribute__((ext_vector_type(16)));

// f32 -> bf16 bits, round-nearest-even (prologue staging only)
__device__ __forceinline__ short f2bf(float f) {
    union { float f; unsigned u; } v; v.f = f;
    unsigned r = (v.u + 0x7FFFu + ((v.u >> 16) & 1u)) >> 16;
    return (short)r;
}
// HW packed f32x2 -> bf16x2 (RNE), gfx950. No builtin — inline asm (T12/m240).
__device__ __forceinline__ unsigned cvt_pk_bf16(float lo, float hi) {
    unsigned r;
    asm("v_cvt_pk_bf16_f32 %0, %1, %2" : "=v"(r) : "v"(lo), "v"(hi));
    return r;
}
// shifted softplus: softplus(x) - ln(2)
__device__ __forceinline__ float ssp(float x) {
    return fmaxf(x, 0.0f) + __logf(1.0f + __expf(-fabsf(x))) - 0.69314718056f;
}

__global__ __launch_bounds__(TPB, 2)   // NOT forced lower (R6 spill lesson)
void cfconv_kernel(const float* __restrict__ af,      // [B,N,D]
                   const float* __restrict__ dist,    // [B,E]
                   const int*   __restrict__ idx_j,   // [E]
                   const int*   __restrict__ seg_i,   // [E] (sorted)
                   const float* __restrict__ centers, // [NRBF]
                   const float* __restrict__ gam,     // [NRBF]
                   const float* __restrict__ W1,      // [NRBF,D]
                   const float* __restrict__ b1,      // [D]
                   const float* __restrict__ W2,      // [D,D]
                   const float* __restrict__ b2,      // [D]
                   float* __restrict__ out)           // [B,N,D]
{
    const int t    = threadIdx.x;        // 0..255
    const int lane = t & 63;
    const int w    = t >> 6;             // wave id 0..3
    const int g    = lane >> 4;          // lane quad 0..3
    const int c0   = lane & 15;
    const int b    = blockIdx.y;
    const int e0   = blockIdx.x * EPB;

    // LDS diet for 3 blocks/CU: 48 KB total.
    // W2f: fragment-ready bf16 W2, loop-resident.
    // A2: h1 exchange [w][c][g][m][j]; ALSO used at prologue to stage W1
    //     fragments (exactly 16 KB each) before hoisting them to registers.
    __shared__ __align__(16) short W2f[4 * 4 * D_ * 8];     // 32 KB
    __shared__ __align__(16) short A2 [4 * 4 * 4 * 16 * 8]; // 16 KB

    // ---- prologue: stage W1 frags (into A2's space) + W2 frags
    for (int i = t; i < NRBF * D_; i += TPB) {
        const int k = i >> 7, n = i & 127;
        A2[(((k >> 5) * 4 + ((k >> 3) & 3)) * D_ + n) * 8 + (k & 7)] = f2bf(W1[i]);
    }
    for (int i = t; i < D_ * D_; i += TPB) {
        const int k = i >> 7, n = i & 127;
        W2f[(((k >> 5) * 4 + ((k >> 3) & 3)) * D_ + n) * 8 + (k & 7)] = f2bf(W2[i]);
    }
    __syncthreads();
    // hoist W1 fragments to registers (R3-verified read formula; 64 VGPRs)
    bf8 w1r[2][8];
    #pragma unroll
    for (int c = 0; c < 2; ++c)
        #pragma unroll
        for (int nt = 0; nt < 8; ++nt)
            w1r[c][nt] = *(const bf8*)&A2[((c * 4 + g) * D_ + nt * 16 + c0) * 8];
    __syncthreads();   // A2 now free for the h1 exchange

    // ---- per-lane constants
    vf8 b1r, b2r;
    #pragma unroll
    for (int nt = 0; nt < 8; ++nt) {
        b1r[nt] = b1[nt * 16 + c0];
        b2r[nt] = b2[nt * 16 + c0];
    }
    // RBF params for this lane's in-register A-fragments (R3-verified):
    // a0 covers k = g*8+j (j=0..7), a1 covers k = 32+g*8+j
    vf16 gkr, ckr;
    #pragma unroll
    for (int j = 0; j < 8; ++j) {
        gkr[j]     = gam[g * 8 + j];
        gkr[8 + j] = gam[32 + g * 8 + j];
        ckr[j]     = centers[g * 8 + j];
        ckr[8 + j] = centers[32 + g * 8 + j];
    }

    const float* dist_b = dist + (size_t)b * E_;
    const float* af_b   = af   + (size_t)b * N_ * D_;
    float*       out_b  = out  + (size_t)b * N_ * D_;

    const int ebase = e0 + w * WCH + g * GCH;   // epilogue: this lane-quad's chunk
    // in-reg Phase A: lane (g,c0) supplies edge row m=c0 of its wave's tile
    const int eArow = e0 + w * WCH + (c0 >> 2) * GCH + (c0 & 3);

    int cur_seg = -1;
    vf8 pend = (vf8)0.0f;

    // ---- prologue: scalar state for tile 0 (prefetched one tile ahead after)
    float dd = dist_b[eArow];
    int idx[4], sgp[4];
    #pragma unroll
    for (int r = 0; r < 4; ++r) {
        idx[r] = idx_j[ebase + r];
        sgp[r] = seg_i[ebase + r];
    }

    for (int s = 0; s < NTILES; ++s) {
        // ===== Phase A: RBF -> A-fragments fully in-register (A1 deleted) =====
        // A-frag layout (16x16x32): lane (g,c0) holds row=c0, k = c*32+g*8+j
        float er0[8], er1[8];
        #pragma unroll
        for (int j = 0; j < 8; ++j) {
            const float x0 = dd - ckr[j];
            const float x1 = dd - ckr[8 + j];
            er0[j] = __expf(-gkr[j] * x0 * x0);
            er1[j] = __expf(-gkr[8 + j] * x1 * x1);
        }
        union { unsigned u[4]; bf8 v; } ua0, ua1;
        #pragma unroll
        for (int q = 0; q < 4; ++q) {
            ua0.u[q] = cvt_pk_bf16(er0[2 * q], er0[2 * q + 1]);
            ua1.u[q] = cvt_pk_bf16(er1[2 * q], er1[2 * q + 1]);
        }
        const bf8 a0 = ua0.v, a1 = ua1.v;

        // ===== prefetch next tile's scalars (drained at barrier (1)) =====
        float ddN = 0.0f;
        int idxN[4] = {0, 0, 0, 0}, sgN[4] = {0, 0, 0, 0};
        if (s + 1 < NTILES) {
            ddN = dist_b[eArow + (s + 1) * 4];
            #pragma unroll
            for (int r = 0; r < 4; ++r) {
                idxN[r] = idx_j[ebase + (s + 1) * 4 + r];
                sgN[r]  = seg_i[ebase + (s + 1) * 4 + r];
            }
        }
        __syncthreads();   // (1) A2 WAR guard: C(s-1) reads done before B(s) writes

        // ===== Phase B: GEMM1 (h1 = rbf @ W1 from registers), ssp, store A2 =====
        {
            f32x4 hh[8];
            #pragma unroll
            for (int nt = 0; nt < 8; ++nt) {
                f32x4 acc = {0.f, 0.f, 0.f, 0.f};
                acc = __builtin_amdgcn_mfma_f32_16x16x32_bf16(a0, w1r[0][nt], acc, 0, 0, 0);
                acc = __builtin_amdgcn_mfma_f32_16x16x32_bf16(a1, w1r[1][nt], acc, 0, 0, 0);
                hh[nt] = acc;
            }
            // value (row m' = g*4+r, col k2 = nt*16+c0) -> A2[w][nt>>1][(nt&1)*2+(c0>>3)][m'][c0&7]
            #pragma unroll
            for (int nt = 0; nt < 8; ++nt) {
                const int shb = (((w * 4 + (nt >> 1)) * 4 + ((nt & 1) * 2 + (c0 >> 3))) * 16) * 8 + (c0 & 7);
                #pragma unroll
                for (int pr = 0; pr < 2; ++pr) {
                    const float h0 = ssp(hh[nt][2 * pr]     + b1r[nt]);
                    const float h1 = ssp(hh[nt][2 * pr + 1] + b1r[nt]);
                    const unsigned pk = cvt_pk_bf16(h0, h1);
                    A2[shb + (g * 4 + 2 * pr)     * 8] = (short)(pk & 0xFFFFu);
                    A2[shb + (g * 4 + 2 * pr + 1) * 8] = (short)(pk >> 16);
                }
            }
        }
        __syncthreads();   // (2) A2 ready

        // ===== Phase C: GEMM2 (filters = h1 @ W2), ssp, gather*filter, scatter =====
        {
            // gather loads issued FIRST in the drain-free window (R8 win)
            float rows[4][8];
            #pragma unroll
            for (int r = 0; r < 4; ++r) {
                const float* rowp = af_b + (size_t)idx[r] * D_ + c0;
                #pragma unroll
                for (int nt = 0; nt < 8; ++nt) rows[r][nt] = rowp[nt * 16];
            }

            const bf8 p0 = *(const bf8*)&A2[(((w * 4 + 0) * 4 + g) * 16 + c0) * 8];
            const bf8 p1 = *(const bf8*)&A2[(((w * 4 + 1) * 4 + g) * 16 + c0) * 8];
            const bf8 p2 = *(const bf8*)&A2[(((w * 4 + 2) * 4 + g) * 16 + c0) * 8];
            const bf8 p3 = *(const bf8*)&A2[(((w * 4 + 3) * 4 + g) * 16 + c0) * 8];
            f32x4 facc[8];
            #pragma unroll
            for (int nt = 0; nt < 8; ++nt) {
                const bf8 w0 = *(const bf8*)&W2f[((0 * 4 + g) * D_ + nt * 16 + c0) * 8];
                const bf8 w1 = *(const bf8*)&W2f[((1 * 4 + g) * D_ + nt * 16 + c0) * 8];
                const bf8 w2 = *(const bf8*)&W2f[((2 * 4 + g) * D_ + nt * 16 + c0) * 8];
                const bf8 w3 = *(const bf8*)&W2f[((3 * 4 + g) * D_ + nt * 16 + c0) * 8];
                f32x4 acc = {0.f, 0.f, 0.f, 0.f};
                acc = __builtin_amdgcn_mfma_f32_16x16x32_bf16(p0, w0, acc, 0, 0, 0);
                acc = __builtin_amdgcn_mfma_f32_16x16x32_bf16(p1, w1, acc, 0, 0, 0);
                acc = __builtin_amdgcn_mfma_f32_16x16x32_bf16(p2, w2, acc, 0, 0, 0);
                acc = __builtin_amdgcn_mfma_f32_16x16x32_bf16(p3, w3, acc, 0, 0, 0);
                facc[nt] = acc;
            }
            // epilogue: lane-quad g owns edges ebase + s*4 + r, lane handles cols c0+16*nt
            #pragma unroll
            for (int r = 0; r < 4; ++r) {
                const int sg = sgp[r];
                vf8 msg;
                #pragma unroll
                for (int nt = 0; nt < 8; ++nt) {
                    const float fv = ssp(facc[nt][r] + b2r[nt]);
                    msg[nt] = rows[r][nt] * fv;
                }
                if (sg != cur_seg) {
                    if (cur_seg >= 0) {
                        float* o = out_b + (size_t)cur_seg * D_ + c0;
                        #pragma unroll
                        for (int nt = 0; nt < 8; ++nt) atomicAdd(o + nt * 16, pend[nt]);
                    }
                    cur_seg = sg;
                    pend = msg;
                } else {
                    pend += msg;
                }
            }
        }

        // commit prefetched scalars for next tile
        dd = ddN;
        #pragma unroll
        for (int r = 0; r < 4; ++r) { idx[r] = idxN[r]; sgp[r] = sgN[r]; }
    }
    if (cur_seg >= 0) {
        float* o = out_b + (size_t)cur_seg * D_ + c0;
        #pragma unroll
        for (int nt = 0; nt < 8; ++nt) atomicAdd(o + nt * 16, pend[nt]);
    }
}

extern "C" void kernel_launch(void* const* d_in, const int* in_sizes, int n_in,
                              void* d_out, int out_size, void* d_ws, size_t ws_size,
                              hipStream_t stream) {
    const float* af      = (const float*)d_in[0];
    const float* dist    = (const float*)d_in[1];
    const int*   idx_j   = (const int*)d_in[2];
    const int*   seg_i   = (const int*)d_in[3];
    const float* centers = (const float*)d_in[4];
    const float* gam     = (const float*)d_in[5];
    const float* W1      = (const float*)d_in[6];
    const float* b1      = (const float*)d_in[7];
    const float* W2      = (const float*)d_in[8];
    const float* b2      = (const float*)d_in[9];
    float* out = (float*)d_out;

    hipMemsetAsync(out, 0, (size_t)out_size * sizeof(float), stream);

    dim3 grid(NBLK, B_);
    cfconv_kernel<<<grid, TPB, 0, stream>>>(af, dist, idx_j, seg_i,
                                            centers, gam, W1, b1, W2, b2, out);
}

// Round 16
// 257.353 us; speedup vs baseline: 1.0005x; 1.0005x over previous
//
#include <hip/hip_runtime.h>
#include <math.h>

#define B_ 2
#define N_ 25000
#define E_ 400000
#define D_ 128
#define NRBF 64

#define TPB 256               // 4 waves
#define TILE 64               // edges per tile-step (16/wave)
#define NTILES 10             // was 25: grid 1250 blocks (~4.9/CU) to FILL the
                              // 3-block/CU capacity the 48 KB LDS diet opened
#define EPB (TILE * NTILES)   // 640 edges per block
#define WCH (EPB / 4)         // 160 edges per wave
#define GCH (EPB / 16)        // 40 edges per (wave, lane-quad) chunk
#define NBLK (E_ / EPB)       // 625 blocks per batch

typedef short bf8   __attribute__((ext_vector_type(8)));   // MFMA A/B frag (8 bf16)
typedef float f32x4 __attribute__((ext_vector_type(4)));   // MFMA C/D frag
typedef float vf8   __attribute__((ext_vector_type(8)));
typedef float vf16  __attribute__((ext_vector_type(16)));

// f32 -> bf16 bits, round-nearest-even (prologue staging only)
__device__ __forceinline__ short f2bf(float f) {
    union { float f; unsigned u; } v; v.f = f;
    unsigned r = (v.u + 0x7FFFu + ((v.u >> 16) & 1u)) >> 16;
    return (short)r;
}
// HW packed f32x2 -> bf16x2 (RNE), gfx950. No builtin — inline asm (T12/m240).
__device__ __forceinline__ unsigned cvt_pk_bf16(float lo, float hi) {
    unsigned r;
    asm("v_cvt_pk_bf16_f32 %0, %1, %2" : "=v"(r) : "v"(lo), "v"(hi));
    return r;
}
// shifted softplus: softplus(x) - ln(2)
__device__ __forceinline__ float ssp(float x) {
    return fmaxf(x, 0.0f) + __logf(1.0f + __expf(-fabsf(x))) - 0.69314718056f;
}

__global__ __launch_bounds__(TPB, 2)   // NOT forced lower (R6 spill lesson)
void cfconv_kernel(const float* __restrict__ af,      // [B,N,D]
                   const float* __restrict__ dist,    // [B,E]
                   const int*   __restrict__ idx_j,   // [E]
                   const int*   __restrict__ seg_i,   // [E] (sorted)
                   const float* __restrict__ centers, // [NRBF]
                   const float* __restrict__ gam,     // [NRBF]
                   const float* __restrict__ W1,      // [NRBF,D]
                   const float* __restrict__ b1,      // [D]
                   const float* __restrict__ W2,      // [D,D]
                   const float* __restrict__ b2,      // [D]
                   float* __restrict__ out)           // [B,N,D]
{
    const int t    = threadIdx.x;        // 0..255
    const int lane = t & 63;
    const int w    = t >> 6;             // wave id 0..3
    const int g    = lane >> 4;          // lane quad 0..3
    const int c0   = lane & 15;
    const int b    = blockIdx.y;
    const int e0   = blockIdx.x * EPB;

    // 48 KB LDS total -> 3 blocks/CU capacity.
    // W2f: fragment-ready bf16 W2, loop-resident.
    // A2: h1 exchange [w][c][g][m][j]; ALSO used at prologue to stage W1
    //     fragments (exactly 16 KB each) before hoisting them to registers.
    __shared__ __align__(16) short W2f[4 * 4 * D_ * 8];     // 32 KB
    __shared__ __align__(16) short A2 [4 * 4 * 4 * 16 * 8]; // 16 KB

    // ---- prologue: stage W1 frags (into A2's space) + W2 frags
    for (int i = t; i < NRBF * D_; i += TPB) {
        const int k = i >> 7, n = i & 127;
        A2[(((k >> 5) * 4 + ((k >> 3) & 3)) * D_ + n) * 8 + (k & 7)] = f2bf(W1[i]);
    }
    for (int i = t; i < D_ * D_; i += TPB) {
        const int k = i >> 7, n = i & 127;
        W2f[(((k >> 5) * 4 + ((k >> 3) & 3)) * D_ + n) * 8 + (k & 7)] = f2bf(W2[i]);
    }
    __syncthreads();
    // hoist W1 fragments to registers (R3-verified read formula; 64 VGPRs)
    bf8 w1r[2][8];
    #pragma unroll
    for (int c = 0; c < 2; ++c)
        #pragma unroll
        for (int nt = 0; nt < 8; ++nt)
            w1r[c][nt] = *(const bf8*)&A2[((c * 4 + g) * D_ + nt * 16 + c0) * 8];
    __syncthreads();   // A2 now free for the h1 exchange

    // ---- per-lane constants
    vf8 b1r, b2r;
    #pragma unroll
    for (int nt = 0; nt < 8; ++nt) {
        b1r[nt] = b1[nt * 16 + c0];
        b2r[nt] = b2[nt * 16 + c0];
    }
    // RBF params for this lane's in-register A-fragments (R3-verified):
    // a0 covers k = g*8+j (j=0..7), a1 covers k = 32+g*8+j
    vf16 gkr, ckr;
    #pragma unroll
    for (int j = 0; j < 8; ++j) {
        gkr[j]     = gam[g * 8 + j];
        gkr[8 + j] = gam[32 + g * 8 + j];
        ckr[j]     = centers[g * 8 + j];
        ckr[8 + j] = centers[32 + g * 8 + j];
    }

    const float* dist_b = dist + (size_t)b * E_;
    const float* af_b   = af   + (size_t)b * N_ * D_;
    float*       out_b  = out  + (size_t)b * N_ * D_;

    const int ebase = e0 + w * WCH + g * GCH;   // epilogue: this lane-quad's chunk
    // in-reg Phase A: lane (g,c0) supplies edge row m=c0 of its wave's tile
    const int eArow = e0 + w * WCH + (c0 >> 2) * GCH + (c0 & 3);

    int cur_seg = -1;
    vf8 pend = (vf8)0.0f;

    // ---- prologue: scalar state for tile 0 (prefetched one tile ahead after)
    float dd = dist_b[eArow];
    int idx[4], sgp[4];
    #pragma unroll
    for (int r = 0; r < 4; ++r) {
        idx[r] = idx_j[ebase + r];
        sgp[r] = seg_i[ebase + r];
    }

    for (int s = 0; s < NTILES; ++s) {
        // ===== Phase A: RBF -> A-fragments fully in-register =====
        // A-frag layout (16x16x32): lane (g,c0) holds row=c0, k = c*32+g*8+j
        float er0[8], er1[8];
        #pragma unroll
        for (int j = 0; j < 8; ++j) {
            const float x0 = dd - ckr[j];
            const float x1 = dd - ckr[8 + j];
            er0[j] = __expf(-gkr[j] * x0 * x0);
            er1[j] = __expf(-gkr[8 + j] * x1 * x1);
        }
        union { unsigned u[4]; bf8 v; } ua0, ua1;
        #pragma unroll
        for (int q = 0; q < 4; ++q) {
            ua0.u[q] = cvt_pk_bf16(er0[2 * q], er0[2 * q + 1]);
            ua1.u[q] = cvt_pk_bf16(er1[2 * q], er1[2 * q + 1]);
        }
        const bf8 a0 = ua0.v, a1 = ua1.v;

        // ===== prefetch next tile's scalars (drained at barrier (1)) =====
        float ddN = 0.0f;
        int idxN[4] = {0, 0, 0, 0}, sgN[4] = {0, 0, 0, 0};
        if (s + 1 < NTILES) {
            ddN = dist_b[eArow + (s + 1) * 4];
            #pragma unroll
            for (int r = 0; r < 4; ++r) {
                idxN[r] = idx_j[ebase + (s + 1) * 4 + r];
                sgN[r]  = seg_i[ebase + (s + 1) * 4 + r];
            }
        }
        __syncthreads();   // (1) A2 WAR guard: C(s-1) reads done before B(s) writes

        // ===== Phase B: GEMM1 (h1 = rbf @ W1 from registers), ssp, store A2 =====
        {
            f32x4 hh[8];
            #pragma unroll
            for (int nt = 0; nt < 8; ++nt) {
                f32x4 acc = {0.f, 0.f, 0.f, 0.f};
                acc = __builtin_amdgcn_mfma_f32_16x16x32_bf16(a0, w1r[0][nt], acc, 0, 0, 0);
                acc = __builtin_amdgcn_mfma_f32_16x16x32_bf16(a1, w1r[1][nt], acc, 0, 0, 0);
                hh[nt] = acc;
            }
            // value (row m' = g*4+r, col k2 = nt*16+c0) -> A2[w][nt>>1][(nt&1)*2+(c0>>3)][m'][c0&7]
            #pragma unroll
            for (int nt = 0; nt < 8; ++nt) {
                const int shb = (((w * 4 + (nt >> 1)) * 4 + ((nt & 1) * 2 + (c0 >> 3))) * 16) * 8 + (c0 & 7);
                #pragma unroll
                for (int pr = 0; pr < 2; ++pr) {
                    const float h0 = ssp(hh[nt][2 * pr]     + b1r[nt]);
                    const float h1 = ssp(hh[nt][2 * pr + 1] + b1r[nt]);
                    const unsigned pk = cvt_pk_bf16(h0, h1);
                    A2[shb + (g * 4 + 2 * pr)     * 8] = (short)(pk & 0xFFFFu);
                    A2[shb + (g * 4 + 2 * pr + 1) * 8] = (short)(pk >> 16);
                }
            }
        }
        __syncthreads();   // (2) A2 ready

        // ===== Phase C: GEMM2 (filters = h1 @ W2), ssp, gather*filter, scatter =====
        {
            // gather loads issued FIRST in the drain-free window (R8 win)
            float rows[4][8];
            #pragma unroll
            for (int r = 0; r < 4; ++r) {
                const float* rowp = af_b + (size_t)idx[r] * D_ + c0;
                #pragma unroll
                for (int nt = 0; nt < 8; ++nt) rows[r][nt] = rowp[nt * 16];
            }

            const bf8 p0 = *(const bf8*)&A2[(((w * 4 + 0) * 4 + g) * 16 + c0) * 8];
            const bf8 p1 = *(const bf8*)&A2[(((w * 4 + 1) * 4 + g) * 16 + c0) * 8];
            const bf8 p2 = *(const bf8*)&A2[(((w * 4 + 2) * 4 + g) * 16 + c0) * 8];
            const bf8 p3 = *(const bf8*)&A2[(((w * 4 + 3) * 4 + g) * 16 + c0) * 8];
            f32x4 facc[8];
            #pragma unroll
            for (int nt = 0; nt < 8; ++nt) {
                const bf8 w0 = *(const bf8*)&W2f[((0 * 4 + g) * D_ + nt * 16 + c0) * 8];
                const bf8 w1 = *(const bf8*)&W2f[((1 * 4 + g) * D_ + nt * 16 + c0) * 8];
                const bf8 w2 = *(const bf8*)&W2f[((2 * 4 + g) * D_ + nt * 16 + c0) * 8];
                const bf8 w3 = *(const bf8*)&W2f[((3 * 4 + g) * D_ + nt * 16 + c0) * 8];
                f32x4 acc = {0.f, 0.f, 0.f, 0.f};
                acc = __builtin_amdgcn_mfma_f32_16x16x32_bf16(p0, w0, acc, 0, 0, 0);
                acc = __builtin_amdgcn_mfma_f32_16x16x32_bf16(p1, w1, acc, 0, 0, 0);
                acc = __builtin_amdgcn_mfma_f32_16x16x32_bf16(p2, w2, acc, 0, 0, 0);
                acc = __builtin_amdgcn_mfma_f32_16x16x32_bf16(p3, w3, acc, 0, 0, 0);
                facc[nt] = acc;
            }
            // epilogue: lane-quad g owns edges ebase + s*4 + r, lane handles cols c0+16*nt
            #pragma unroll
            for (int r = 0; r < 4; ++r) {
                const int sg = sgp[r];
                vf8 msg;
                #pragma unroll
                for (int nt = 0; nt < 8; ++nt) {
                    const float fv = ssp(facc[nt][r] + b2r[nt]);
                    msg[nt] = rows[r][nt] * fv;
                }
                if (sg != cur_seg) {
                    if (cur_seg >= 0) {
                        float* o = out_b + (size_t)cur_seg * D_ + c0;
                        #pragma unroll
                        for (int nt = 0; nt < 8; ++nt) atomicAdd(o + nt * 16, pend[nt]);
                    }
                    cur_seg = sg;
                    pend = msg;
                } else {
                    pend += msg;
                }
            }
        }

        // commit prefetched scalars for next tile
        dd = ddN;
        #pragma unroll
        for (int r = 0; r < 4; ++r) { idx[r] = idxN[r]; sgp[r] = sgN[r]; }
    }
    if (cur_seg >= 0) {
        float* o = out_b + (size_t)cur_seg * D_ + c0;
        #pragma unroll
        for (int nt = 0; nt < 8; ++nt) atomicAdd(o + nt * 16, pend[nt]);
    }
}

extern "C" void kernel_launch(void* const* d_in, const int* in_sizes, int n_in,
                              void* d_out, int out_size, void* d_ws, size_t ws_size,
                              hipStream_t stream) {
    const float* af      = (const float*)d_in[0];
    const float* dist    = (const float*)d_in[1];
    const int*   idx_j   = (const int*)d_in[2];
    const int*   seg_i   = (const int*)d_in[3];
    const float* centers = (const float*)d_in[4];
    const float* gam     = (const float*)d_in[5];
    const float* W1      = (const float*)d_in[6];
    const float* b1      = (const float*)d_in[7];
    const float* W2      = (const float*)d_in[8];
    const float* b2      = (const float*)d_in[9];
    float* out = (float*)d_out;

    hipMemsetAsync(out, 0, (size_t)out_size * sizeof(float), stream);

    dim3 grid(NBLK, B_);
    cfconv_kernel<<<grid, TPB, 0, stream>>>(af, dist, idx_j, seg_i,
                                            centers, gam, W1, b1, W2, b2, out);
}

// Round 17
// 245.879 us; speedup vs baseline: 1.0472x; 1.0467x over previous
//
#include <hip/hip_runtime.h>
#include <math.h>

#define B_ 2
#define N_ 25000
#define E_ 400000
#define D_ 128
#define NRBF 64

#define TPB 256               // 4 waves
#define TILE 64               // edges per tile-step (16/wave)
#define NTILES 25             // R15 config (best measured)
#define EPB (TILE * NTILES)   // 1600 edges per block
#define WCH (EPB / 4)         // 400 edges per wave
#define GCH (EPB / 16)        // 100 edges per (wave, lane-quad) chunk
#define NBLK (E_ / EPB)       // 250 blocks per batch

typedef short bf8   __attribute__((ext_vector_type(8)));   // MFMA A/B frag (8 bf16)
typedef float f32x4 __attribute__((ext_vector_type(4)));   // MFMA C/D frag
typedef float vf8   __attribute__((ext_vector_type(8)));
typedef float vf16  __attribute__((ext_vector_type(16)));

// f32 -> bf16 bits, round-nearest-even (prologue staging only)
__device__ __forceinline__ short f2bf(float f) {
    union { float f; unsigned u; } v; v.f = f;
    unsigned r = (v.u + 0x7FFFu + ((v.u >> 16) & 1u)) >> 16;
    return (short)r;
}
// HW packed f32x2 -> bf16x2 (RNE), gfx950. No builtin — inline asm (T12/m240).
__device__ __forceinline__ unsigned cvt_pk_bf16(float lo, float hi) {
    unsigned r;
    asm("v_cvt_pk_bf16_f32 %0, %1, %2" : "=v"(r) : "v"(lo), "v"(hi));
    return r;
}
// shifted softplus: softplus(x) - ln(2)
__device__ __forceinline__ float ssp(float x) {
    return fmaxf(x, 0.0f) + __logf(1.0f + __expf(-fabsf(x))) - 0.69314718056f;
}

__global__ __launch_bounds__(TPB, 2)
void cfconv_kernel(const float* __restrict__ af,      // [B,N,D]
                   const float* __restrict__ dist,    // [B,E]
                   const int*   __restrict__ idx_j,   // [E]
                   const int*   __restrict__ seg_i,   // [E] (sorted)
                   const float* __restrict__ centers, // [NRBF]
                   const float* __restrict__ gam,     // [NRBF]
                   const float* __restrict__ W1,      // [NRBF,D]
                   const float* __restrict__ b1,      // [D]
                   const float* __restrict__ W2,      // [D,D]
                   const float* __restrict__ b2,      // [D]
                   float* __restrict__ out)           // [B,N,D]
{
    const int t    = threadIdx.x;        // 0..255
    const int lane = t & 63;
    const int w    = t >> 6;             // wave id 0..3
    const int g    = lane >> 4;          // lane quad 0..3
    const int c0   = lane & 15;
    const int b    = blockIdx.y;
    const int e0   = blockIdx.x * EPB;

    // 48 KB LDS. W2f read-only after prologue; A2 is WAVE-PRIVATE ([w] index
    // on every loop access) -> no block barrier needed in the main loop.
    __shared__ __align__(16) short W2f[4 * 4 * D_ * 8];     // 32 KB
    __shared__ __align__(16) short A2 [4 * 4 * 4 * 16 * 8]; // 16 KB

    // ---- prologue: stage W1 frags (into A2's space) + W2 frags
    for (int i = t; i < NRBF * D_; i += TPB) {
        const int k = i >> 7, n = i & 127;
        A2[(((k >> 5) * 4 + ((k >> 3) & 3)) * D_ + n) * 8 + (k & 7)] = f2bf(W1[i]);
    }
    for (int i = t; i < D_ * D_; i += TPB) {
        const int k = i >> 7, n = i & 127;
        W2f[(((k >> 5) * 4 + ((k >> 3) & 3)) * D_ + n) * 8 + (k & 7)] = f2bf(W2[i]);
    }
    __syncthreads();
    // hoist W1 fragments to registers (R3-verified read formula; 64 VGPRs)
    bf8 w1r[2][8];
    #pragma unroll
    for (int c = 0; c < 2; ++c)
        #pragma unroll
        for (int nt = 0; nt < 8; ++nt)
            w1r[c][nt] = *(const bf8*)&A2[((c * 4 + g) * D_ + nt * 16 + c0) * 8];
    __syncthreads();   // A2 now free for the h1 exchange (last block barrier)

    // ---- per-lane constants
    vf8 b1r, b2r;
    #pragma unroll
    for (int nt = 0; nt < 8; ++nt) {
        b1r[nt] = b1[nt * 16 + c0];
        b2r[nt] = b2[nt * 16 + c0];
    }
    // RBF params for this lane's in-register A-fragments (R3-verified):
    // a0 covers k = g*8+j (j=0..7), a1 covers k = 32+g*8+j
    vf16 gkr, ckr;
    #pragma unroll
    for (int j = 0; j < 8; ++j) {
        gkr[j]     = gam[g * 8 + j];
        gkr[8 + j] = gam[32 + g * 8 + j];
        ckr[j]     = centers[g * 8 + j];
        ckr[8 + j] = centers[32 + g * 8 + j];
    }

    const float* dist_b = dist + (size_t)b * E_;
    const float* af_b   = af   + (size_t)b * N_ * D_;
    float*       out_b  = out  + (size_t)b * N_ * D_;

    const int ebase = e0 + w * WCH + g * GCH;   // epilogue: this lane-quad's chunk
    // in-reg Phase A: lane (g,c0) supplies edge row m=c0 of its wave's tile
    const int eArow = e0 + w * WCH + (c0 >> 2) * GCH + (c0 & 3);

    int cur_seg = -1;
    vf8 pend = (vf8)0.0f;

    // ---- prologue: scalar state for tile 0 (prefetched one tile ahead after)
    float dd = dist_b[eArow];
    int idx[4], sgp[4];
    #pragma unroll
    for (int r = 0; r < 4; ++r) {
        idx[r] = idx_j[ebase + r];
        sgp[r] = seg_i[ebase + r];
    }

    for (int s = 0; s < NTILES; ++s) {
        // ===== Phase A: RBF -> A-fragments fully in-register =====
        // A-frag layout (16x16x32): lane (g,c0) holds row=c0, k = c*32+g*8+j
        float er0[8], er1[8];
        #pragma unroll
        for (int j = 0; j < 8; ++j) {
            const float x0 = dd - ckr[j];
            const float x1 = dd - ckr[8 + j];
            er0[j] = __expf(-gkr[j] * x0 * x0);
            er1[j] = __expf(-gkr[8 + j] * x1 * x1);
        }
        union { unsigned u[4]; bf8 v; } ua0, ua1;
        #pragma unroll
        for (int q = 0; q < 4; ++q) {
            ua0.u[q] = cvt_pk_bf16(er0[2 * q], er0[2 * q + 1]);
            ua1.u[q] = cvt_pk_bf16(er1[2 * q], er1[2 * q + 1]);
        }
        const bf8 a0 = ua0.v, a1 = ua1.v;

        // ===== prefetch next tile's scalars (consumed next iteration; with no
        // barriers they stay in flight under Phase B/C compute) =====
        float ddN = 0.0f;
        int idxN[4] = {0, 0, 0, 0}, sgN[4] = {0, 0, 0, 0};
        if (s + 1 < NTILES) {
            ddN = dist_b[eArow + (s + 1) * 4];
            #pragma unroll
            for (int r = 0; r < 4; ++r) {
                idxN[r] = idx_j[ebase + (s + 1) * 4 + r];
                sgN[r]  = seg_i[ebase + (s + 1) * 4 + r];
            }
        }
        // NO __syncthreads: A2 is wave-private; per-wave in-order LDS pipe +
        // the fence below provide all required ordering.

        // ===== Phase B: GEMM1 (h1 = rbf @ W1 from registers), ssp, store A2 =====
        {
            f32x4 hh[8];
            #pragma unroll
            for (int nt = 0; nt < 8; ++nt) {
                f32x4 acc = {0.f, 0.f, 0.f, 0.f};
                acc = __builtin_amdgcn_mfma_f32_16x16x32_bf16(a0, w1r[0][nt], acc, 0, 0, 0);
                acc = __builtin_amdgcn_mfma_f32_16x16x32_bf16(a1, w1r[1][nt], acc, 0, 0, 0);
                hh[nt] = acc;
            }
            // value (row m' = g*4+r, col k2 = nt*16+c0) -> A2[w][nt>>1][(nt&1)*2+(c0>>3)][m'][c0&7]
            #pragma unroll
            for (int nt = 0; nt < 8; ++nt) {
                const int shb = (((w * 4 + (nt >> 1)) * 4 + ((nt & 1) * 2 + (c0 >> 3))) * 16) * 8 + (c0 & 7);
                #pragma unroll
                for (int pr = 0; pr < 2; ++pr) {
                    const float h0 = ssp(hh[nt][2 * pr]     + b1r[nt]);
                    const float h1 = ssp(hh[nt][2 * pr + 1] + b1r[nt]);
                    const unsigned pk = cvt_pk_bf16(h0, h1);
                    A2[shb + (g * 4 + 2 * pr)     * 8] = (short)(pk & 0xFFFFu);
                    A2[shb + (g * 4 + 2 * pr + 1) * 8] = (short)(pk >> 16);
                }
            }
        }
        // Wave-local RAW fence: A2 writes complete before the reads below.
        // (rule #18: sched_barrier required so reg-only ops can't hoist past)
        asm volatile("s_waitcnt lgkmcnt(0)" ::: "memory");
        __builtin_amdgcn_sched_barrier(0);

        // ===== Phase C: GEMM2 (filters = h1 @ W2), ssp, gather*filter, scatter =====
        {
            // gather loads issued FIRST (R8 win): addresses prefetched last
            // tile; GEMM2's MFMAs + LDS reads cover the latency.
            float rows[4][8];
            #pragma unroll
            for (int r = 0; r < 4; ++r) {
                const float* rowp = af_b + (size_t)idx[r] * D_ + c0;
                #pragma unroll
                for (int nt = 0; nt < 8; ++nt) rows[r][nt] = rowp[nt * 16];
            }

            const bf8 p0 = *(const bf8*)&A2[(((w * 4 + 0) * 4 + g) * 16 + c0) * 8];
            const bf8 p1 = *(const bf8*)&A2[(((w * 4 + 1) * 4 + g) * 16 + c0) * 8];
            const bf8 p2 = *(const bf8*)&A2[(((w * 4 + 2) * 4 + g) * 16 + c0) * 8];
            const bf8 p3 = *(const bf8*)&A2[(((w * 4 + 3) * 4 + g) * 16 + c0) * 8];
            f32x4 facc[8];
            #pragma unroll
            for (int nt = 0; nt < 8; ++nt) {
                const bf8 w0 = *(const bf8*)&W2f[((0 * 4 + g) * D_ + nt * 16 + c0) * 8];
                const bf8 w1 = *(const bf8*)&W2f[((1 * 4 + g) * D_ + nt * 16 + c0) * 8];
                const bf8 w2 = *(const bf8*)&W2f[((2 * 4 + g) * D_ + nt * 16 + c0) * 8];
                const bf8 w3 = *(const bf8*)&W2f[((3 * 4 + g) * D_ + nt * 16 + c0) * 8];
                f32x4 acc = {0.f, 0.f, 0.f, 0.f};
                acc = __builtin_amdgcn_mfma_f32_16x16x32_bf16(p0, w0, acc, 0, 0, 0);
                acc = __builtin_amdgcn_mfma_f32_16x16x32_bf16(p1, w1, acc, 0, 0, 0);
                acc = __builtin_amdgcn_mfma_f32_16x16x32_bf16(p2, w2, acc, 0, 0, 0);
                acc = __builtin_amdgcn_mfma_f32_16x16x32_bf16(p3, w3, acc, 0, 0, 0);
                facc[nt] = acc;
            }
            // epilogue: lane-quad g owns edges ebase + s*4 + r, lane handles cols c0+16*nt
            #pragma unroll
            for (int r = 0; r < 4; ++r) {
                const int sg = sgp[r];
                vf8 msg;
                #pragma unroll
                for (int nt = 0; nt < 8; ++nt) {
                    const float fv = ssp(facc[nt][r] + b2r[nt]);
                    msg[nt] = rows[r][nt] * fv;
                }
                if (sg != cur_seg) {
                    if (cur_seg >= 0) {
                        float* o = out_b + (size_t)cur_seg * D_ + c0;
                        #pragma unroll
                        for (int nt = 0; nt < 8; ++nt) atomicAdd(o + nt * 16, pend[nt]);
                    }
                    cur_seg = sg;
                    pend = msg;
                } else {
                    pend += msg;
                }
            }
        }

        // commit prefetched scalars for next tile
        dd = ddN;
        #pragma unroll
        for (int r = 0; r < 4; ++r) { idx[r] = idxN[r]; sgp[r] = sgN[r]; }
        // Cross-iteration WAR (this tile's A2 reads vs next tile's writes):
        // per-wave in-order LDS FIFO orders the accesses in HW; this compiler
        // fence prevents issue reordering across the iteration boundary.
        asm volatile("" ::: "memory");
    }
    if (cur_seg >= 0) {
        float* o = out_b + (size_t)cur_seg * D_ + c0;
        #pragma unroll
        for (int nt = 0; nt < 8; ++nt) atomicAdd(o + nt * 16, pend[nt]);
    }
}

extern "C" void kernel_launch(void* const* d_in, const int* in_sizes, int n_in,
                              void* d_out, int out_size, void* d_ws, size_t ws_size,
                              hipStream_t stream) {
    const float* af      = (const float*)d_in[0];
    const float* dist    = (const float*)d_in[1];
    const int*   idx_j   = (const int*)d_in[2];
    const int*   seg_i   = (const int*)d_in[3];
    const float* centers = (const float*)d_in[4];
    const float* gam     = (const float*)d_in[5];
    const float* W1      = (const float*)d_in[6];
    const float* b1      = (const float*)d_in[7];
    const float* W2      = (const float*)d_in[8];
    const float* b2      = (const float*)d_in[9];
    float* out = (float*)d_out;

    hipMemsetAsync(out, 0, (size_t)out_size * sizeof(float), stream);

    dim3 grid(NBLK, B_);
    cfconv_kernel<<<grid, TPB, 0, stream>>>(af, dist, idx_j, seg_i,
                                            centers, gam, W1, b1, W2, b2, out);
}